// Round 4
// baseline (305.490 us; speedup 1.0000x reference)
//
#include <hip/hip_runtime.h>
#include <math.h>

typedef float4 f4;
typedef __bf16 bf16x8 __attribute__((ext_vector_type(8)));
typedef float f32x4 __attribute__((ext_vector_type(4)));

static constexpr int kV = 10000, kL = 6, kDPL = 500;
static constexpr int kB = 64, kT = 32, kN = 40, kBT = 2048;
static constexpr int kC = 14, kKPER = 736;   // 13 full chunks + last = 13 steps + 16-tail
static constexpr int kSteps = kKPER / 32;    // 23
static constexpr int kTailSteps = 13;        // (10000 - 13*736) >> 5
static constexpr int kVT = 79;               // ceil(10000/128) v-tiles
static constexpr int kOntoLd = 10240;        // ontoT row stride (k-pad)
static constexpr int kVpad = 10112;          // coWT rows (n-pad)

#define MFMA16 __builtin_amdgcn_mfma_f32_16x16x32_bf16

__device__ __forceinline__ bf16x8 cvt8(f4 a, f4 b) {
  bf16x8 r;
  r[0] = (__bf16)a.x; r[1] = (__bf16)a.y; r[2] = (__bf16)a.z; r[3] = (__bf16)a.w;
  r[4] = (__bf16)b.x; r[5] = (__bf16)b.y; r[6] = (__bf16)b.z; r[7] = (__bf16)b.w;
  return r;
}

// ---------------- fp32 -> bf16 elementwise ----------------
__global__ __launch_bounds__(256) void mmore_cvt_bf16(
    const float* __restrict__ in, __bf16* __restrict__ out, int n) {
  int i = (blockIdx.x * 256 + threadIdx.x) * 8;
  if (i < n) {
    f4 a = *(const f4*)(in + i), b = *(const f4*)(in + i + 4);
    *(bf16x8*)(out + i) = cvt8(a, b);
  }
}

// ---------------- transpose+cvt: out[n][k] (bf16, k-pad/n-pad zeros) = in[k][n]
__global__ __launch_bounds__(256) void mmore_trcvt(
    const float* __restrict__ in, __bf16* __restrict__ out,
    int K, int N, int Kpad) {
  int t = threadIdx.x;
  int n = blockIdx.y * 16 + (t & 15);
  int kb = (blockIdx.x * 16 + (t >> 4)) * 8;
  bf16x8 r;
  #pragma unroll
  for (int i = 0; i < 8; ++i) {
    int k = kb + i;
    float v = (k < K && n < N) ? in[(size_t)k * N + n] : 0.f;
    r[i] = (__bf16)v;
  }
  *(bf16x8*)(out + (size_t)n * Kpad + kb) = r;
}

// ---------------- ehrV = l2norm(sum_n ehr_table[dxseqs]) ----------------
__global__ __launch_bounds__(128) void mmore_ehrv(
    const int* __restrict__ dxseqs, const float* __restrict__ ehr_table,
    float* __restrict__ ehrV) {
  int bt = blockIdx.x, t = threadIdx.x;
  const int* row = dxseqs + bt * kN;
  float acc = 0.f;
  for (int n = 0; n < kN; ++n) acc += ehr_table[(size_t)row[n] * 128 + t];
  float v = acc * acc;
  #pragma unroll
  for (int off = 32; off; off >>= 1) v += __shfl_down(v, off);
  __shared__ float red[2];
  if ((t & 63) == 0) red[t >> 6] = v;
  __syncthreads();
  float ss = red[0] + red[1];
  float inv = 1.f / fmaxf(sqrtf(ss), 1e-12f);
  ehrV[bt * 128 + t] = acc * inv;
}

// ---------------- GRAM scores via MFMA: s = Wc . tanh([el,ea]@Wa + ba) + bc --
__global__ __launch_bounds__(256) void mmore_scores_mfma(
    const __bf16* __restrict__ otb, const int* __restrict__ leaves,
    const int* __restrict__ anc, const __bf16* __restrict__ WaT,
    const float* __restrict__ ba, const float* __restrict__ Wc,
    const float* __restrict__ bc, float* __restrict__ s_out) {
  int t = threadIdx.x, wave = t >> 6, lane = t & 63, lm = lane & 15, lg = lane >> 4;
  int r0 = blockIdx.x * 32;
  int rA0 = r0 + lm, rA1 = rA0 + 16;
  int v0 = rA0 / 6, l0 = rA0 - v0 * 6, v1 = rA1 / 6, l1 = rA1 - v1 * 6;
  const __bf16* pL0 = otb + (size_t)leaves[v0 * 6 + l0] * 128;
  const __bf16* pA0 = otb + (size_t)anc[v0 * 6 + l0] * 128;
  const __bf16* pL1 = otb + (size_t)leaves[v1 * 6 + l1] * 128;
  const __bf16* pA1 = otb + (size_t)anc[v1 * 6 + l1] * 128;
  const __bf16* bp = WaT + (size_t)(wave * 32 + lm) * 256 + lg * 8;
  f32x4 acc[2][2] = {};
  #pragma unroll
  for (int kb = 0; kb < 256; kb += 32) {
    int k = kb + lg * 8;
    const __bf16* s0 = (k < 128) ? (pL0 + k) : (pA0 + (k - 128));
    const __bf16* s1 = (k < 128) ? (pL1 + k) : (pA1 + (k - 128));
    bf16x8 a0 = *(const bf16x8*)s0;
    bf16x8 a1 = *(const bf16x8*)s1;
    bf16x8 b0 = *(const bf16x8*)(bp + kb);
    bf16x8 b1 = *(const bf16x8*)(bp + kb + 16 * 256);
    acc[0][0] = MFMA16(a0, b0, acc[0][0], 0, 0, 0);
    acc[0][1] = MFMA16(a0, b1, acc[0][1], 0, 0, 0);
    acc[1][0] = MFMA16(a1, b0, acc[1][0], 0, 0, 0);
    acc[1][1] = MFMA16(a1, b1, acc[1][1], 0, 0, 0);
  }
  __shared__ float red[4][32];
  float bcv = bc[0];
  #pragma unroll
  for (int mf = 0; mf < 2; ++mf) {
    #pragma unroll
    for (int j = 0; j < 4; ++j) {
      float p = 0.f;
      #pragma unroll
      for (int nf = 0; nf < 2; ++nf) {
        int c = wave * 32 + nf * 16 + lm;
        p += tanhf(acc[mf][nf][j] + ba[c]) * Wc[c];
      }
      #pragma unroll
      for (int off = 8; off; off >>= 1) p += __shfl_xor(p, off);
      if (lm == 0) red[wave][mf * 16 + lg * 4 + j] = p;
    }
  }
  __syncthreads();
  if (t < 32) s_out[r0 + t] = red[0][t] + red[1][t] + red[2][t] + red[3][t] + bcv;
}

// ---------------- onto_all[v] = softmax_l(s) . ea ; row V = 0 ----------------
__global__ __launch_bounds__(128) void mmore_onto(
    const float* __restrict__ ot, const int* __restrict__ anc,
    const float* __restrict__ s_in, float* __restrict__ onto_all) {
  int v = blockIdx.x, t = threadIdx.x;
  if (v == kV) { onto_all[(size_t)v * 128 + t] = 0.f; return; }
  __shared__ float sv[kL];
  __shared__ int aidx[kL];
  if (t < kL) { sv[t] = s_in[v * kL + t]; aidx[t] = anc[v * kL + t]; }
  __syncthreads();
  float mx = sv[0];
  #pragma unroll
  for (int l = 1; l < kL; ++l) mx = fmaxf(mx, sv[l]);
  float e[kL], sum = 0.f;
  #pragma unroll
  for (int l = 0; l < kL; ++l) { e[l] = expf(sv[l] - mx); sum += e[l]; }
  float acc = 0.f;
  #pragma unroll
  for (int l = 0; l < kL; ++l)
    acc += (e[l] / sum) * ot[(size_t)aidx[l] * 128 + t];
  onto_all[(size_t)v * 128 + t] = acc;
}

// ---------------- ontoV partials via MFMA: X(bt,v) @ onto_all, 14-way K-split --
__global__ __launch_bounds__(256) void mmore_ontov_mfma(
    const float* __restrict__ X, const __bf16* __restrict__ BT,
    float* __restrict__ part) {
  int t = threadIdx.x, wave = t >> 6, lane = t & 63, lm = lane & 15, lg = lane >> 4;
  int btile = blockIdx.x & 63, chunk = blockIdx.x >> 6;
  int r0 = btile * 32, vbase = chunk * kKPER;
  int bt0 = r0 + lm, bt1 = bt0 + 16;
  const float* a0 = X + ((size_t)(bt0 & 31) * kB + (bt0 >> 5)) * kV + vbase + lg * 8;
  const float* a1 = X + ((size_t)(bt1 & 31) * kB + (bt1 >> 5)) * kV + vbase + lg * 8;
  const __bf16* bp = BT + (size_t)(wave * 32 + lm) * kOntoLd + vbase + lg * 8;
  f32x4 acc[2][2] = {};

  auto step = [&](int kb) {
    f4 x0 = *(const f4*)(a0 + kb), x1 = *(const f4*)(a0 + kb + 4);
    f4 y0 = *(const f4*)(a1 + kb), y1 = *(const f4*)(a1 + kb + 4);
    bf16x8 b0 = *(const bf16x8*)(bp + kb);
    bf16x8 b1 = *(const bf16x8*)(bp + kb + 16 * kOntoLd);
    bf16x8 af0 = cvt8(x0, x1), af1 = cvt8(y0, y1);
    acc[0][0] = MFMA16(af0, b0, acc[0][0], 0, 0, 0);
    acc[0][1] = MFMA16(af0, b1, acc[0][1], 0, 0, 0);
    acc[1][0] = MFMA16(af1, b0, acc[1][0], 0, 0, 0);
    acc[1][1] = MFMA16(af1, b1, acc[1][1], 0, 0, 0);
  };

  if (chunk != kC - 1) {
    #pragma unroll
    for (int s = 0; s < kSteps; ++s) step(s * 32);
  } else {
    #pragma unroll
    for (int s = 0; s < kTailSteps; ++s) step(s * 32);
    // 16-wide tail (k = vbase + 416 .. +431); lg>=2 lanes OOB -> zero
    {
      int kb = kTailSteps * 32;
      f4 z = make_float4(0.f, 0.f, 0.f, 0.f);
      f4 x0 = z, x1 = z, y0 = z, y1 = z;
      if (lg < 2) {
        x0 = *(const f4*)(a0 + kb); x1 = *(const f4*)(a0 + kb + 4);
        y0 = *(const f4*)(a1 + kb); y1 = *(const f4*)(a1 + kb + 4);
      }
      bf16x8 b0 = *(const bf16x8*)(bp + kb);
      bf16x8 b1 = *(const bf16x8*)(bp + kb + 16 * kOntoLd);
      bf16x8 af0 = cvt8(x0, x1), af1 = cvt8(y0, y1);
      acc[0][0] = MFMA16(af0, b0, acc[0][0], 0, 0, 0);
      acc[0][1] = MFMA16(af0, b1, acc[0][1], 0, 0, 0);
      acc[1][0] = MFMA16(af1, b0, acc[1][0], 0, 0, 0);
      acc[1][1] = MFMA16(af1, b1, acc[1][1], 0, 0, 0);
    }
  }
  #pragma unroll
  for (int mf = 0; mf < 2; ++mf)
    #pragma unroll
    for (int nf = 0; nf < 2; ++nf) {
      int col = wave * 32 + nf * 16 + lm;
      #pragma unroll
      for (int j = 0; j < 4; ++j) {
        int row = r0 + mf * 16 + lg * 4 + j;
        part[((size_t)chunk * kBT + row) * 128 + col] = acc[mf][nf][j];
      }
    }
}

__global__ __launch_bounds__(256) void mmore_creduce(
    const float* __restrict__ part, float* __restrict__ out) {
  int i = blockIdx.x * 256 + threadIdx.x;
  const int S = kBT * 128;
  float a = 0.f;
  #pragma unroll
  for (int c = 0; c < kC; ++c) a += part[(size_t)c * S + i];
  out[i] = a;
}

// ---------------- loss via MFMA: z = ehrV@coW + cob; partials {Σe^z, Σp·z, Σp}
__global__ __launch_bounds__(256) void mmore_loss_mfma(
    const float* __restrict__ ehrV, const __bf16* __restrict__ coWT,
    const float* __restrict__ cob, const float* __restrict__ X,
    float* __restrict__ epart) {
  int t = threadIdx.x, wave = t >> 6, lane = t & 63, lm = lane & 15, lg = lane >> 4;
  int vtile = blockIdx.x, btile = blockIdx.y;
  int r0 = btile * 32, vb = vtile * 128;
  const float* a0 = ehrV + (size_t)(r0 + lm) * 128 + lg * 8;
  const float* a1 = a0 + 16 * 128;
  const __bf16* bp = coWT + (size_t)(vb + wave * 32 + lm) * 128 + lg * 8;
  f32x4 acc[2][2] = {};
  #pragma unroll
  for (int kb = 0; kb < 128; kb += 32) {
    f4 x0 = *(const f4*)(a0 + kb), x1 = *(const f4*)(a0 + kb + 4);
    f4 y0 = *(const f4*)(a1 + kb), y1 = *(const f4*)(a1 + kb + 4);
    bf16x8 af0 = cvt8(x0, x1), af1 = cvt8(y0, y1);
    bf16x8 b0 = *(const bf16x8*)(bp + kb);
    bf16x8 b1 = *(const bf16x8*)(bp + kb + 16 * 128);
    acc[0][0] = MFMA16(af0, b0, acc[0][0], 0, 0, 0);
    acc[0][1] = MFMA16(af0, b1, acc[0][1], 0, 0, 0);
    acc[1][0] = MFMA16(af1, b0, acc[1][0], 0, 0, 0);
    acc[1][1] = MFMA16(af1, b1, acc[1][1], 0, 0, 0);
  }
  float se[2][4] = {}, spz[2][4] = {}, sp[2][4] = {};
  #pragma unroll
  for (int nf = 0; nf < 2; ++nf) {
    int c = vb + wave * 32 + nf * 16 + lm;
    if (c < kV) {
      float cb = cob[c];
      #pragma unroll
      for (int mf = 0; mf < 2; ++mf) {
        #pragma unroll
        for (int j = 0; j < 4; ++j) {
          int row = r0 + mf * 16 + lg * 4 + j;
          float z = acc[mf][nf][j] + cb;
          float p = X[((size_t)(row & 31) * kB + (row >> 5)) * kV + c];
          se[mf][j] += __expf(z);
          spz[mf][j] += p * z;
          sp[mf][j] += p;
        }
      }
    }
  }
  __shared__ float red[4][32][3];
  #pragma unroll
  for (int mf = 0; mf < 2; ++mf)
    #pragma unroll
    for (int j = 0; j < 4; ++j) {
      float a = se[mf][j], b = spz[mf][j], d = sp[mf][j];
      #pragma unroll
      for (int off = 8; off; off >>= 1) {
        a += __shfl_xor(a, off); b += __shfl_xor(b, off); d += __shfl_xor(d, off);
      }
      if (lm == 0) {
        int r = mf * 16 + lg * 4 + j;
        red[wave][r][0] = a; red[wave][r][1] = b; red[wave][r][2] = d;
      }
    }
  __syncthreads();
  if (t < 96) {
    int r = t / 3, q = t - (t / 3) * 3;
    float s = red[0][r][q] + red[1][r][q] + red[2][r][q] + red[3][r][q];
    epart[((size_t)vtile * kBT + r0 + r) * 3 + q] = s;
  }
}

__global__ __launch_bounds__(256) void mmore_ereduce(
    const float* __restrict__ epart, float* __restrict__ term) {
  int bt = blockIdx.x * 256 + threadIdx.x;
  float S = 0.f, PZ = 0.f, PS = 0.f;
  for (int c = 0; c < kVT; ++c) {
    size_t o = ((size_t)c * kBT + bt) * 3;
    S += epart[o]; PZ += epart[o + 1]; PS += epart[o + 2];
  }
  term[bt] = PZ - PS * logf(S);
}

__global__ __launch_bounds__(256) void mmore_lossfin(
    const float* __restrict__ term, float* __restrict__ out) {
  int t = threadIdx.x;
  float a = 0.f;
  for (int i = t; i < kBT; i += 256) a += term[i];
  #pragma unroll
  for (int off = 32; off; off >>= 1) a += __shfl_down(a, off);
  __shared__ float red[4];
  if ((t & 63) == 0) red[t >> 6] = a;
  __syncthreads();
  if (t == 0) out[0] = -(10.f / 64.f) * (red[0] + red[1] + red[2] + red[3]);
}

// ---------------- generic MFMA: C[M][128] (+=) A[M][128] @ WT[n][ldWT]+koff --
__global__ __launch_bounds__(256) void mmore_gemm_mfma(
    const float* __restrict__ A, const __bf16* __restrict__ WT,
    int ldWT, int koff, const float* __restrict__ bias,
    float* __restrict__ C, int M, int accumulate) {
  int t = threadIdx.x, wave = t >> 6, lane = t & 63, lm = lane & 15, lg = lane >> 4;
  int r0 = blockIdx.x * 32;
  int row0 = r0 + lm, row1 = row0 + 16;
  bool ok0 = row0 < M, ok1 = row1 < M;
  const float* a0 = A + (size_t)row0 * 128 + lg * 8;
  const float* a1 = A + (size_t)row1 * 128 + lg * 8;
  const __bf16* bp = WT + (size_t)(wave * 32 + lm) * ldWT + koff + lg * 8;
  int ld16 = 16 * ldWT;
  f32x4 acc[2][2] = {};
  #pragma unroll
  for (int kb = 0; kb < 128; kb += 32) {
    f4 x0 = make_float4(0, 0, 0, 0), x1 = x0, y0 = x0, y1 = x0;
    if (ok0) { x0 = *(const f4*)(a0 + kb); x1 = *(const f4*)(a0 + kb + 4); }
    if (ok1) { y0 = *(const f4*)(a1 + kb); y1 = *(const f4*)(a1 + kb + 4); }
    bf16x8 af0 = cvt8(x0, x1), af1 = cvt8(y0, y1);
    bf16x8 b0 = *(const bf16x8*)(bp + kb);
    bf16x8 b1 = *(const bf16x8*)(bp + kb + ld16);
    acc[0][0] = MFMA16(af0, b0, acc[0][0], 0, 0, 0);
    acc[0][1] = MFMA16(af0, b1, acc[0][1], 0, 0, 0);
    acc[1][0] = MFMA16(af1, b0, acc[1][0], 0, 0, 0);
    acc[1][1] = MFMA16(af1, b1, acc[1][1], 0, 0, 0);
  }
  #pragma unroll
  for (int mf = 0; mf < 2; ++mf)
    #pragma unroll
    for (int nf = 0; nf < 2; ++nf) {
      int col = wave * 32 + nf * 16 + lm;
      #pragma unroll
      for (int j = 0; j < 4; ++j) {
        int row = r0 + mf * 16 + lg * 4 + j;
        if (row < M) {
          float v = acc[mf][nf][j];
          if (bias) v += bias[col];
          if (accumulate) v += C[(size_t)row * 128 + col];
          C[(size_t)row * 128 + col] = v;
        }
      }
    }
}

// ---------------- per-(b,t): Bahdanau attention -> tn = tanh(l2norm(vs2)) ----
__device__ __forceinline__ float mmore_block_sum(float v, float* red) {
  int t = threadIdx.x;
  #pragma unroll
  for (int off = 32; off; off >>= 1) v += __shfl_down(v, off);
  if ((t & 63) == 0) red[t >> 6] = v;
  __syncthreads();
  if (t == 0) red[0] = red[0] + red[1] + red[2] + red[3];
  __syncthreads();
  return red[0];
}

__global__ __launch_bounds__(256) void mmore_attn(
    const int* __restrict__ dxseqs, const float* __restrict__ base,
    const float* __restrict__ pe, const float* __restrict__ po,
    const float* __restrict__ combW, const float* __restrict__ combB,
    const float* __restrict__ ehr_table, const float* __restrict__ onto_all,
    float* __restrict__ tn) {
  __shared__ float base_s[128];
  __shared__ int idx_s[kN];
  __shared__ float scp[kN][2];
  __shared__ float attn_s[64];
  __shared__ float red[4];
  int bt = blockIdx.x, t = threadIdx.x;
  if (t < 128) base_s[t] = base[bt * 128 + t];
  if (t < kN) idx_s[t] = dxseqs[bt * kN + t];
  __syncthreads();
  int c = t & 127, half = t >> 7, wid = t >> 6, lane = t & 63;
  float cw = combW[c];
  for (int n2 = 0; n2 < kN / 2; ++n2) {
    int n = n2 * 2 + half;
    int id = idx_s[n];
    float x = base_s[c] + pe[(size_t)id * 128 + c] + po[(size_t)id * 128 + c];
    float val = tanhf(x) * cw;
    #pragma unroll
    for (int off = 32; off; off >>= 1) val += __shfl_down(val, off);
    if (lane == 0) scp[n][wid & 1] = val;
  }
  __syncthreads();
  if (t < 64) {
    float s = (t < kN) ? (scp[t][0] + scp[t][1] + combB[0]) : -1e30f;
    float mx = s;
    #pragma unroll
    for (int off = 32; off; off >>= 1) mx = fmaxf(mx, __shfl_xor(mx, off));
    float e = (t < kN) ? __expf(s - mx) : 0.f;
    float sm = e;
    #pragma unroll
    for (int off = 32; off; off >>= 1) sm += __shfl_xor(sm, off);
    attn_s[t] = e / sm;
  }
  __syncthreads();
  float acc = 0.f;
  {
    const float* tab = (t < 128) ? ehr_table : onto_all;
    int j = t & 127;
    for (int n = 0; n < kN; ++n)
      acc += attn_s[n] * tab[(size_t)idx_s[n] * 128 + j];
  }
  float ss = mmore_block_sum(acc * acc, red);
  float inv = 1.f / fmaxf(sqrtf(ss), 1e-12f);
  tn[(size_t)bt * 256 + t] = tanhf(acc * inv);
}

// ---------------- dp head GEMM: u[2048][512] = tn@dpWT + dpB ----------------
__global__ __launch_bounds__(256) void mmore_dpgemm(
    const float* __restrict__ tn, const __bf16* __restrict__ dpWT,
    const float* __restrict__ dpB, float* __restrict__ u) {
  int t = threadIdx.x, wave = t >> 6, lane = t & 63, lm = lane & 15, lg = lane >> 4;
  int c0 = blockIdx.x * 128, r0 = blockIdx.y * 32;
  const float* a0 = tn + (size_t)(r0 + lm) * 256 + lg * 8;
  const float* a1 = a0 + 16 * 256;
  const __bf16* bp = dpWT + (size_t)(c0 + wave * 32 + lm) * 256 + lg * 8;
  f32x4 acc[2][2] = {};
  #pragma unroll
  for (int kb = 0; kb < 256; kb += 32) {
    f4 x0 = *(const f4*)(a0 + kb), x1 = *(const f4*)(a0 + kb + 4);
    f4 y0 = *(const f4*)(a1 + kb), y1 = *(const f4*)(a1 + kb + 4);
    bf16x8 af0 = cvt8(x0, x1), af1 = cvt8(y0, y1);
    bf16x8 b0 = *(const bf16x8*)(bp + kb);
    bf16x8 b1 = *(const bf16x8*)(bp + kb + 16 * 256);
    acc[0][0] = MFMA16(af0, b0, acc[0][0], 0, 0, 0);
    acc[0][1] = MFMA16(af0, b1, acc[0][1], 0, 0, 0);
    acc[1][0] = MFMA16(af1, b0, acc[1][0], 0, 0, 0);
    acc[1][1] = MFMA16(af1, b1, acc[1][1], 0, 0, 0);
  }
  #pragma unroll
  for (int mf = 0; mf < 2; ++mf)
    #pragma unroll
    for (int nf = 0; nf < 2; ++nf) {
      int col = c0 + wave * 32 + nf * 16 + lm;
      float bias = (col < kDPL) ? dpB[col] : 0.f;
      #pragma unroll
      for (int j = 0; j < 4; ++j) {
        int row = r0 + mf * 16 + lg * 4 + j;
        u[(size_t)row * 512 + col] = acc[mf][nf][j] + bias;
      }
    }
}

// ---------------- dp softmax over 500 cols ----------------
__global__ __launch_bounds__(128) void mmore_dpsoft(
    const float* __restrict__ u, float* __restrict__ out) {
  int bt = blockIdx.x, t = threadIdx.x;
  __shared__ float red[2];
  float v[4]; float mx = -1e30f;
  #pragma unroll
  for (int i = 0; i < 4; ++i) {
    int c = t + i * 128;
    v[i] = (c < kDPL) ? u[(size_t)bt * 512 + c] : -1e30f;
    mx = fmaxf(mx, v[i]);
  }
  #pragma unroll
  for (int off = 32; off; off >>= 1) mx = fmaxf(mx, __shfl_xor(mx, off));
  if ((t & 63) == 0) red[t >> 6] = mx;
  __syncthreads();
  mx = fmaxf(red[0], red[1]);
  __syncthreads();
  float e[4], s = 0.f;
  #pragma unroll
  for (int i = 0; i < 4; ++i) {
    int c = t + i * 128;
    e[i] = (c < kDPL) ? __expf(v[i] - mx) : 0.f;
    s += e[i];
  }
  #pragma unroll
  for (int off = 32; off; off >>= 1) s += __shfl_xor(s, off);
  if ((t & 63) == 0) red[t >> 6] = s;
  __syncthreads();
  float invS = 1.f / (red[0] + red[1]);
  #pragma unroll
  for (int i = 0; i < 4; ++i) {
    int c = t + i * 128;
    if (c < kDPL) out[(size_t)bt * kDPL + c] = e[i] * invS;
  }
}

extern "C" void kernel_launch(void* const* d_in, const int* in_sizes, int n_in,
                              void* d_out, int out_size, void* d_ws, size_t ws_size,
                              hipStream_t stream) {
  const int*   dxseqs     = (const int*)d_in[0];
  const float* dx_onehot  = (const float*)d_in[1];
  const int*   leaves     = (const int*)d_in[2];
  const int*   ancestors  = (const int*)d_in[3];
  const float* onto_table = (const float*)d_in[4];
  const float* onto_Wa    = (const float*)d_in[5];
  const float* onto_ba    = (const float*)d_in[6];
  const float* onto_Wc    = (const float*)d_in[7];
  const float* onto_bc    = (const float*)d_in[8];
  const float* ehr_table  = (const float*)d_in[9];
  const float* attn_W     = (const float*)d_in[10];
  const float* attn_b     = (const float*)d_in[11];
  const float* comb_W     = (const float*)d_in[12];
  const float* comb_b     = (const float*)d_in[13];
  const float* co_W       = (const float*)d_in[14];
  const float* co_b       = (const float*)d_in[15];
  const float* dp_W       = (const float*)d_in[16];
  const float* dp_b       = (const float*)d_in[17];
  float* out = (float*)d_out;

  // ---- workspace (float slots), ~26.4 MB total ----
  // Layout REORDERED so cpart (14 * 2048 * 128 = 3,670,016 fl) fits the alias
  // span peR..coWT (3,956,992 fl). coWT's trcvt runs AFTER creduce.
  float* ws = (float*)d_ws;
  size_t off = 0;
  auto alloc = [&](size_t n) { float* p = ws + off; off += n; return p; };
  float* onto_all = alloc((size_t)(kV + 1) * 128);              // 1,280,128
  float* s_sc     = alloc((size_t)kV * kL);                     //    60,000
  float* ehrV     = alloc((size_t)kBT * 128);                   //   262,144
  float* ontoV    = alloc((size_t)kBT * 128);                   //   262,144
  __bf16* ontoT   = (__bf16*)alloc((size_t)128 * kOntoLd / 2);  //   655,360 fl
  __bf16* attn_WT = (__bf16*)alloc((size_t)128 * 512 / 2);      //    32,768 fl
  __bf16* dpWT    = (__bf16*)alloc((size_t)512 * 256 / 2);      //    65,536 fl
  __bf16* WaT     = (__bf16*)alloc((size_t)128 * 256 / 2);      //    16,384 fl
  float* peR      = alloc((size_t)(kV + 1) * 128);              // 1,280,128
  float* poR      = alloc((size_t)(kV + 1) * 128);              // 1,280,128
  float* basep    = alloc((size_t)kBT * 128);                   //   262,144
  float* epart    = alloc((size_t)kVT * kBT * 3);               //   485,376
  float* term     = alloc(kBT);                                 //     2,048
  __bf16* coWT    = (__bf16*)alloc((size_t)kVpad * 128 / 2);    //   647,168 fl
  // time-disjoint aliases (all within peR..coWT span):
  __bf16* ot_bf = (__bf16*)peR;   // dead after scores; before cpart
  float*  cpart = peR;            // written by ontov, dead after creduce (before
                                  // coWT trcvt / loss / pe / po writes)
  float*  u     = peR;            // written after pe last read (attn)
  float*  tn    = ehrV;           // written after ehrV/ontoV last reads

  // ---- prep (coWT deferred until after creduce) ----
  mmore_cvt_bf16<<<663, 256, 0, stream>>>(onto_table, ot_bf, 10600 * 128);
  mmore_trcvt<<<dim3(2, 8), 256, 0, stream>>>(onto_Wa, WaT, 256, 128, 256);
  mmore_trcvt<<<dim3(4, 8), 256, 0, stream>>>(attn_W, attn_WT, 512, 128, 512);
  mmore_trcvt<<<dim3(2, 32), 256, 0, stream>>>(dp_W, dpWT, 256, kDPL, 256);

  mmore_ehrv<<<kBT, 128, 0, stream>>>(dxseqs, ehr_table, ehrV);
  mmore_scores_mfma<<<(kV * kL) / 32, 256, 0, stream>>>(
      ot_bf, leaves, ancestors, WaT, onto_ba, onto_Wc, onto_bc, s_sc);
  mmore_onto<<<kV + 1, 128, 0, stream>>>(onto_table, ancestors, s_sc, onto_all);
  mmore_trcvt<<<dim3(80, 8), 256, 0, stream>>>(onto_all, ontoT, kV, 128, kOntoLd);
  mmore_ontov_mfma<<<64 * kC, 256, 0, stream>>>(dx_onehot, ontoT, cpart);
  mmore_creduce<<<(kBT * 128) / 256, 256, 0, stream>>>(cpart, ontoV);
  mmore_trcvt<<<dim3(1, 632), 256, 0, stream>>>(co_W, coWT, 128, kV, 128);
  mmore_loss_mfma<<<dim3(kVT, 64), 256, 0, stream>>>(ehrV, coWT, co_b, dx_onehot, epart);
  mmore_ereduce<<<kBT / 256, 256, 0, stream>>>(epart, term);
  mmore_lossfin<<<1, 256, 0, stream>>>(term, out + (size_t)kBT * kDPL);
  mmore_gemm_mfma<<<313, 256, 0, stream>>>(ehr_table, attn_WT, 512, 256, nullptr, peR, kV + 1, 0);
  mmore_gemm_mfma<<<313, 256, 0, stream>>>(onto_all, attn_WT, 512, 384, nullptr, poR, kV + 1, 0);
  mmore_gemm_mfma<<<64, 256, 0, stream>>>(ontoV, attn_WT, 512, 0, nullptr, basep, kBT, 0);
  mmore_gemm_mfma<<<64, 256, 0, stream>>>(ehrV, attn_WT, 512, 128, attn_b, basep, kBT, 1);
  mmore_attn<<<kBT, 256, 0, stream>>>(dxseqs, basep, peR, poR, comb_W, comb_b,
                                      ehr_table, onto_all, tn);
  mmore_dpgemm<<<dim3(4, 64), 256, 0, stream>>>(tn, dpWT, dp_b, u);
  mmore_dpsoft<<<kBT, 128, 0, stream>>>(u, out);
}

// Round 5
// 282.418 us; speedup vs baseline: 1.0817x; 1.0817x over previous
//
#include <hip/hip_runtime.h>
#include <math.h>

typedef float4 f4;
typedef __bf16 bf16x8 __attribute__((ext_vector_type(8)));
typedef float f32x4 __attribute__((ext_vector_type(4)));

static constexpr int kV = 10000, kL = 6, kDPL = 500;
static constexpr int kB = 64, kT = 32, kN = 40, kBT = 2048;
static constexpr int kC = 13;                // K-chunks of 768 (+16 tail on last)
static constexpr int kVT = 79;               // ceil(10000/128) v-tiles
static constexpr int kOntoLd = 10240;        // ontoT row stride (k-pad, zero-filled)
static constexpr int kVpad = 10112;          // coWT rows (n-pad)

#define MFMA16 __builtin_amdgcn_mfma_f32_16x16x32_bf16

__device__ __forceinline__ bf16x8 cvt8(f4 a, f4 b) {
  bf16x8 r;
  r[0] = (__bf16)a.x; r[1] = (__bf16)a.y; r[2] = (__bf16)a.z; r[3] = (__bf16)a.w;
  r[4] = (__bf16)b.x; r[5] = (__bf16)b.y; r[6] = (__bf16)b.z; r[7] = (__bf16)b.w;
  return r;
}

// ---------------- fp32 -> bf16 elementwise ----------------
__global__ __launch_bounds__(256) void mmore_cvt_bf16(
    const float* __restrict__ in, __bf16* __restrict__ out, int n) {
  int i = (blockIdx.x * 256 + threadIdx.x) * 8;
  if (i < n) {
    f4 a = *(const f4*)(in + i), b = *(const f4*)(in + i + 4);
    *(bf16x8*)(out + i) = cvt8(a, b);
  }
}

// ---------------- transpose+cvt: out[n][k] (bf16, k-pad/n-pad zeros) = in[k][n]
__global__ __launch_bounds__(256) void mmore_trcvt(
    const float* __restrict__ in, __bf16* __restrict__ out,
    int K, int N, int Kpad) {
  int t = threadIdx.x;
  int n = blockIdx.y * 16 + (t & 15);
  int kb = (blockIdx.x * 16 + (t >> 4)) * 8;
  bf16x8 r;
  #pragma unroll
  for (int i = 0; i < 8; ++i) {
    int k = kb + i;
    float v = (k < K && n < N) ? in[(size_t)k * N + n] : 0.f;
    r[i] = (__bf16)v;
  }
  *(bf16x8*)(out + (size_t)n * Kpad + kb) = r;
}

// ---------------- ehrV = l2norm(sum_n ehr_table[dxseqs]) ----------------
__global__ __launch_bounds__(128) void mmore_ehrv(
    const int* __restrict__ dxseqs, const float* __restrict__ ehr_table,
    float* __restrict__ ehrV) {
  int bt = blockIdx.x, t = threadIdx.x;
  const int* row = dxseqs + bt * kN;
  float acc = 0.f;
  for (int n = 0; n < kN; ++n) acc += ehr_table[(size_t)row[n] * 128 + t];
  float v = acc * acc;
  #pragma unroll
  for (int off = 32; off; off >>= 1) v += __shfl_down(v, off);
  __shared__ float red[2];
  if ((t & 63) == 0) red[t >> 6] = v;
  __syncthreads();
  float ss = red[0] + red[1];
  float inv = 1.f / fmaxf(sqrtf(ss), 1e-12f);
  ehrV[bt * 128 + t] = acc * inv;
}

// ---------------- GRAM scores via MFMA: s = Wc . tanh([el,ea]@Wa + ba) + bc --
__global__ __launch_bounds__(256) void mmore_scores_mfma(
    const __bf16* __restrict__ otb, const int* __restrict__ leaves,
    const int* __restrict__ anc, const __bf16* __restrict__ WaT,
    const float* __restrict__ ba, const float* __restrict__ Wc,
    const float* __restrict__ bc, float* __restrict__ s_out) {
  int t = threadIdx.x, wave = t >> 6, lane = t & 63, lm = lane & 15, lg = lane >> 4;
  int r0 = blockIdx.x * 32;
  int rA0 = r0 + lm, rA1 = rA0 + 16;
  int v0 = rA0 / 6, l0 = rA0 - v0 * 6, v1 = rA1 / 6, l1 = rA1 - v1 * 6;
  const __bf16* pL0 = otb + (size_t)leaves[v0 * 6 + l0] * 128;
  const __bf16* pA0 = otb + (size_t)anc[v0 * 6 + l0] * 128;
  const __bf16* pL1 = otb + (size_t)leaves[v1 * 6 + l1] * 128;
  const __bf16* pA1 = otb + (size_t)anc[v1 * 6 + l1] * 128;
  const __bf16* bp = WaT + (size_t)(wave * 32 + lm) * 256 + lg * 8;
  f32x4 acc[2][2] = {};
  #pragma unroll
  for (int kb = 0; kb < 256; kb += 32) {
    int k = kb + lg * 8;
    const __bf16* s0 = (k < 128) ? (pL0 + k) : (pA0 + (k - 128));
    const __bf16* s1 = (k < 128) ? (pL1 + k) : (pA1 + (k - 128));
    bf16x8 a0 = *(const bf16x8*)s0;
    bf16x8 a1 = *(const bf16x8*)s1;
    bf16x8 b0 = *(const bf16x8*)(bp + kb);
    bf16x8 b1 = *(const bf16x8*)(bp + kb + 16 * 256);
    acc[0][0] = MFMA16(a0, b0, acc[0][0], 0, 0, 0);
    acc[0][1] = MFMA16(a0, b1, acc[0][1], 0, 0, 0);
    acc[1][0] = MFMA16(a1, b0, acc[1][0], 0, 0, 0);
    acc[1][1] = MFMA16(a1, b1, acc[1][1], 0, 0, 0);
  }
  __shared__ float red[4][32];
  float bcv = bc[0];
  #pragma unroll
  for (int mf = 0; mf < 2; ++mf) {
    #pragma unroll
    for (int j = 0; j < 4; ++j) {
      float p = 0.f;
      #pragma unroll
      for (int nf = 0; nf < 2; ++nf) {
        int c = wave * 32 + nf * 16 + lm;
        p += tanhf(acc[mf][nf][j] + ba[c]) * Wc[c];
      }
      #pragma unroll
      for (int off = 8; off; off >>= 1) p += __shfl_xor(p, off);
      if (lm == 0) red[wave][mf * 16 + lg * 4 + j] = p;
    }
  }
  __syncthreads();
  if (t < 32) s_out[r0 + t] = red[0][t] + red[1][t] + red[2][t] + red[3][t] + bcv;
}

// ---------------- onto_all[v] = softmax_l(s) . ea ; row V = 0 ----------------
__global__ __launch_bounds__(128) void mmore_onto(
    const float* __restrict__ ot, const int* __restrict__ anc,
    const float* __restrict__ s_in, float* __restrict__ onto_all) {
  int v = blockIdx.x, t = threadIdx.x;
  if (v == kV) { onto_all[(size_t)v * 128 + t] = 0.f; return; }
  __shared__ float sv[kL];
  __shared__ int aidx[kL];
  if (t < kL) { sv[t] = s_in[v * kL + t]; aidx[t] = anc[v * kL + t]; }
  __syncthreads();
  float mx = sv[0];
  #pragma unroll
  for (int l = 1; l < kL; ++l) mx = fmaxf(mx, sv[l]);
  float e[kL], sum = 0.f;
  #pragma unroll
  for (int l = 0; l < kL; ++l) { e[l] = expf(sv[l] - mx); sum += e[l]; }
  float acc = 0.f;
  #pragma unroll
  for (int l = 0; l < kL; ++l)
    acc += (e[l] / sum) * ot[(size_t)aidx[l] * 128 + t];
  onto_all[(size_t)v * 128 + t] = acc;
}

// ---- ontoV partials via MFMA + LDS-staged A: X(bt,v)@onto_all, 13-way K-split
// BM=16, BK=64, grid (128 btiles x 13 chunks) = 1664 blocks, 4.4 KB LDS.
__global__ __launch_bounds__(256) void mmore_ontov_mfma(
    const float* __restrict__ X, const __bf16* __restrict__ BT,
    float* __restrict__ part) {
  __shared__ __align__(16) float a_s[16][68];
  int t = threadIdx.x, wave = t >> 6, lane = t & 63, lm = lane & 15, lg = lane >> 4;
  int btile = blockIdx.x & 127;
  int chunk = blockIdx.x >> 7;
  int r0 = btile * 16, vbase = chunk * 768;
  int srow = t >> 4, scol = (t & 15) * 4;
  int sbt = r0 + srow;
  const float* xrow = X + ((size_t)(sbt & 31) * kB + (sbt >> 5)) * kV + vbase;
  const __bf16* bp0 = BT + (size_t)(wave * 32 + lm) * kOntoLd + vbase + lg * 8;
  const __bf16* bp1 = bp0 + (size_t)16 * kOntoLd;
  f32x4 acc0 = {}, acc1 = {};
  bool last = (chunk == kC - 1);
  f4 xv = *(const f4*)(xrow + scol);
  #pragma unroll
  for (int s = 0; s < 12; ++s) {
    __syncthreads();
    *(f4*)&a_s[srow][scol] = xv;
    __syncthreads();
    if (s < 11) {
      xv = *(const f4*)(xrow + (s + 1) * 64 + scol);
    } else if (last) {
      f4 z = make_float4(0.f, 0.f, 0.f, 0.f);
      xv = (scol < 16) ? *(const f4*)(xrow + 768 + scol) : z;  // 16-wide tail
    }
    #pragma unroll
    for (int h = 0; h < 2; ++h) {
      int kb = s * 64 + h * 32;
      f4 x0 = *(const f4*)&a_s[lm][h * 32 + lg * 8];
      f4 x1 = *(const f4*)&a_s[lm][h * 32 + lg * 8 + 4];
      bf16x8 af = cvt8(x0, x1);
      bf16x8 b0 = *(const bf16x8*)(bp0 + kb);
      bf16x8 b1 = *(const bf16x8*)(bp1 + kb);
      acc0 = MFMA16(af, b0, acc0, 0, 0, 0);
      acc1 = MFMA16(af, b1, acc1, 0, 0, 0);
    }
  }
  if (last) {  // tail 16 k (B rows 10000..10047 are zero-padded)
    __syncthreads();
    *(f4*)&a_s[srow][scol] = xv;
    __syncthreads();
    #pragma unroll
    for (int h = 0; h < 2; ++h) {
      int kb = 768 + h * 32;
      f4 x0 = *(const f4*)&a_s[lm][h * 32 + lg * 8];
      f4 x1 = *(const f4*)&a_s[lm][h * 32 + lg * 8 + 4];
      bf16x8 af = cvt8(x0, x1);
      bf16x8 b0 = *(const bf16x8*)(bp0 + kb);
      bf16x8 b1 = *(const bf16x8*)(bp1 + kb);
      acc0 = MFMA16(af, b0, acc0, 0, 0, 0);
      acc1 = MFMA16(af, b1, acc1, 0, 0, 0);
    }
  }
  #pragma unroll
  for (int j = 0; j < 4; ++j) {
    int row = r0 + lg * 4 + j;
    int col = wave * 32 + lm;
    part[((size_t)chunk * kBT + row) * 128 + col] = acc0[j];
    part[((size_t)chunk * kBT + row) * 128 + col + 16] = acc1[j];
  }
}

__global__ __launch_bounds__(256) void mmore_creduce(
    const float* __restrict__ part, float* __restrict__ out) {
  int i = blockIdx.x * 256 + threadIdx.x;
  const int S = kBT * 128;
  float a = 0.f;
  #pragma unroll
  for (int c = 0; c < kC; ++c) a += part[(size_t)c * S + i];
  out[i] = a;
}

// ---------------- loss via MFMA: z = ehrV@coW + cob; partials {Σe^z, Σp·z, Σp}
__global__ __launch_bounds__(256) void mmore_loss_mfma(
    const float* __restrict__ ehrV, const __bf16* __restrict__ coWT,
    const float* __restrict__ cob, const float* __restrict__ X,
    float* __restrict__ epart) {
  int t = threadIdx.x, wave = t >> 6, lane = t & 63, lm = lane & 15, lg = lane >> 4;
  int vtile = blockIdx.x, btile = blockIdx.y;
  int r0 = btile * 32, vb = vtile * 128;
  const float* a0 = ehrV + (size_t)(r0 + lm) * 128 + lg * 8;
  const float* a1 = a0 + 16 * 128;
  const __bf16* bp = coWT + (size_t)(vb + wave * 32 + lm) * 128 + lg * 8;
  f32x4 acc[2][2] = {};
  #pragma unroll
  for (int kb = 0; kb < 128; kb += 32) {
    f4 x0 = *(const f4*)(a0 + kb), x1 = *(const f4*)(a0 + kb + 4);
    f4 y0 = *(const f4*)(a1 + kb), y1 = *(const f4*)(a1 + kb + 4);
    bf16x8 af0 = cvt8(x0, x1), af1 = cvt8(y0, y1);
    bf16x8 b0 = *(const bf16x8*)(bp + kb);
    bf16x8 b1 = *(const bf16x8*)(bp + kb + 16 * 128);
    acc[0][0] = MFMA16(af0, b0, acc[0][0], 0, 0, 0);
    acc[0][1] = MFMA16(af0, b1, acc[0][1], 0, 0, 0);
    acc[1][0] = MFMA16(af1, b0, acc[1][0], 0, 0, 0);
    acc[1][1] = MFMA16(af1, b1, acc[1][1], 0, 0, 0);
  }
  float se[2][4] = {}, spz[2][4] = {}, sp[2][4] = {};
  #pragma unroll
  for (int nf = 0; nf < 2; ++nf) {
    int c = vb + wave * 32 + nf * 16 + lm;
    if (c < kV) {
      float cb = cob[c];
      #pragma unroll
      for (int mf = 0; mf < 2; ++mf) {
        #pragma unroll
        for (int j = 0; j < 4; ++j) {
          int row = r0 + mf * 16 + lg * 4 + j;
          float z = acc[mf][nf][j] + cb;
          float p = X[((size_t)(row & 31) * kB + (row >> 5)) * kV + c];
          se[mf][j] += __expf(z);
          spz[mf][j] += p * z;
          sp[mf][j] += p;
        }
      }
    }
  }
  __shared__ float red[4][32][3];
  #pragma unroll
  for (int mf = 0; mf < 2; ++mf)
    #pragma unroll
    for (int j = 0; j < 4; ++j) {
      float a = se[mf][j], b = spz[mf][j], d = sp[mf][j];
      #pragma unroll
      for (int off = 8; off; off >>= 1) {
        a += __shfl_xor(a, off); b += __shfl_xor(b, off); d += __shfl_xor(d, off);
      }
      if (lm == 0) {
        int r = mf * 16 + lg * 4 + j;
        red[wave][r][0] = a; red[wave][r][1] = b; red[wave][r][2] = d;
      }
    }
  __syncthreads();
  if (t < 96) {
    int r = t / 3, q = t - (t / 3) * 3;
    float s = red[0][r][q] + red[1][r][q] + red[2][r][q] + red[3][r][q];
    epart[((size_t)vtile * kBT + r0 + r) * 3 + q] = s;
  }
}

__global__ __launch_bounds__(256) void mmore_ereduce(
    const float* __restrict__ epart, float* __restrict__ term) {
  int bt = blockIdx.x * 256 + threadIdx.x;
  float S = 0.f, PZ = 0.f, PS = 0.f;
  for (int c = 0; c < kVT; ++c) {
    size_t o = ((size_t)c * kBT + bt) * 3;
    S += epart[o]; PZ += epart[o + 1]; PS += epart[o + 2];
  }
  term[bt] = PZ - PS * logf(S);
}

__global__ __launch_bounds__(256) void mmore_lossfin(
    const float* __restrict__ term, float* __restrict__ out) {
  int t = threadIdx.x;
  float a = 0.f;
  for (int i = t; i < kBT; i += 256) a += term[i];
  #pragma unroll
  for (int off = 32; off; off >>= 1) a += __shfl_down(a, off);
  __shared__ float red[4];
  if ((t & 63) == 0) red[t >> 6] = a;
  __syncthreads();
  if (t == 0) out[0] = -(10.f / 64.f) * (red[0] + red[1] + red[2] + red[3]);
}

// ---------------- generic MFMA: C[M][128] (+=) A[M][128] @ WT[n][ldWT]+koff --
__global__ __launch_bounds__(256) void mmore_gemm_mfma(
    const float* __restrict__ A, const __bf16* __restrict__ WT,
    int ldWT, int koff, const float* __restrict__ bias,
    float* __restrict__ C, int M, int accumulate) {
  int t = threadIdx.x, wave = t >> 6, lane = t & 63, lm = lane & 15, lg = lane >> 4;
  int r0 = blockIdx.x * 32;
  int row0 = r0 + lm, row1 = row0 + 16;
  bool ok0 = row0 < M, ok1 = row1 < M;
  const float* a0 = A + (size_t)row0 * 128 + lg * 8;
  const float* a1 = A + (size_t)row1 * 128 + lg * 8;
  const __bf16* bp = WT + (size_t)(wave * 32 + lm) * ldWT + koff + lg * 8;
  int ld16 = 16 * ldWT;
  f32x4 acc[2][2] = {};
  #pragma unroll
  for (int kb = 0; kb < 128; kb += 32) {
    f4 x0 = make_float4(0, 0, 0, 0), x1 = x0, y0 = x0, y1 = x0;
    if (ok0) { x0 = *(const f4*)(a0 + kb); x1 = *(const f4*)(a0 + kb + 4); }
    if (ok1) { y0 = *(const f4*)(a1 + kb); y1 = *(const f4*)(a1 + kb + 4); }
    bf16x8 af0 = cvt8(x0, x1), af1 = cvt8(y0, y1);
    bf16x8 b0 = *(const bf16x8*)(bp + kb);
    bf16x8 b1 = *(const bf16x8*)(bp + kb + ld16);
    acc[0][0] = MFMA16(af0, b0, acc[0][0], 0, 0, 0);
    acc[0][1] = MFMA16(af0, b1, acc[0][1], 0, 0, 0);
    acc[1][0] = MFMA16(af1, b0, acc[1][0], 0, 0, 0);
    acc[1][1] = MFMA16(af1, b1, acc[1][1], 0, 0, 0);
  }
  #pragma unroll
  for (int mf = 0; mf < 2; ++mf)
    #pragma unroll
    for (int nf = 0; nf < 2; ++nf) {
      int col = wave * 32 + nf * 16 + lm;
      #pragma unroll
      for (int j = 0; j < 4; ++j) {
        int row = r0 + mf * 16 + lg * 4 + j;
        if (row < M) {
          float v = acc[mf][nf][j];
          if (bias) v += bias[col];
          if (accumulate) v += C[(size_t)row * 128 + col];
          C[(size_t)row * 128 + col] = v;
        }
      }
    }
}

// ---------------- per-(b,t): Bahdanau attention -> tn = tanh(l2norm(vs2)) ----
__device__ __forceinline__ float mmore_block_sum(float v, float* red) {
  int t = threadIdx.x;
  #pragma unroll
  for (int off = 32; off; off >>= 1) v += __shfl_down(v, off);
  if ((t & 63) == 0) red[t >> 6] = v;
  __syncthreads();
  if (t == 0) red[0] = red[0] + red[1] + red[2] + red[3];
  __syncthreads();
  return red[0];
}

__global__ __launch_bounds__(256) void mmore_attn(
    const int* __restrict__ dxseqs, const float* __restrict__ base,
    const float* __restrict__ pe, const float* __restrict__ po,
    const float* __restrict__ combW, const float* __restrict__ combB,
    const float* __restrict__ ehr_table, const float* __restrict__ onto_all,
    float* __restrict__ tn) {
  __shared__ float base_s[128];
  __shared__ int idx_s[kN];
  __shared__ float scp[kN][2];
  __shared__ float attn_s[64];
  __shared__ float red[4];
  int bt = blockIdx.x, t = threadIdx.x;
  if (t < 128) base_s[t] = base[bt * 128 + t];
  if (t < kN) idx_s[t] = dxseqs[bt * kN + t];
  __syncthreads();
  int c = t & 127, half = t >> 7, wid = t >> 6, lane = t & 63;
  float cw = combW[c];
  for (int n2 = 0; n2 < kN / 2; ++n2) {
    int n = n2 * 2 + half;
    int id = idx_s[n];
    float x = base_s[c] + pe[(size_t)id * 128 + c] + po[(size_t)id * 128 + c];
    float val = tanhf(x) * cw;
    #pragma unroll
    for (int off = 32; off; off >>= 1) val += __shfl_down(val, off);
    if (lane == 0) scp[n][wid & 1] = val;
  }
  __syncthreads();
  if (t < 64) {
    float s = (t < kN) ? (scp[t][0] + scp[t][1] + combB[0]) : -1e30f;
    float mx = s;
    #pragma unroll
    for (int off = 32; off; off >>= 1) mx = fmaxf(mx, __shfl_xor(mx, off));
    float e = (t < kN) ? __expf(s - mx) : 0.f;
    float sm = e;
    #pragma unroll
    for (int off = 32; off; off >>= 1) sm += __shfl_xor(sm, off);
    attn_s[t] = e / sm;
  }
  __syncthreads();
  float acc = 0.f;
  {
    const float* tab = (t < 128) ? ehr_table : onto_all;
    int j = t & 127;
    for (int n = 0; n < kN; ++n)
      acc += attn_s[n] * tab[(size_t)idx_s[n] * 128 + j];
  }
  float ss = mmore_block_sum(acc * acc, red);
  float inv = 1.f / fmaxf(sqrtf(ss), 1e-12f);
  tn[(size_t)bt * 256 + t] = tanhf(acc * inv);
}

// ---------------- dp head GEMM: u[2048][512] = tn@dpWT + dpB ----------------
__global__ __launch_bounds__(256) void mmore_dpgemm(
    const float* __restrict__ tn, const __bf16* __restrict__ dpWT,
    const float* __restrict__ dpB, float* __restrict__ u) {
  int t = threadIdx.x, wave = t >> 6, lane = t & 63, lm = lane & 15, lg = lane >> 4;
  int c0 = blockIdx.x * 128, r0 = blockIdx.y * 32;
  const float* a0 = tn + (size_t)(r0 + lm) * 256 + lg * 8;
  const float* a1 = a0 + 16 * 256;
  const __bf16* bp = dpWT + (size_t)(c0 + wave * 32 + lm) * 256 + lg * 8;
  f32x4 acc[2][2] = {};
  #pragma unroll
  for (int kb = 0; kb < 256; kb += 32) {
    f4 x0 = *(const f4*)(a0 + kb), x1 = *(const f4*)(a0 + kb + 4);
    f4 y0 = *(const f4*)(a1 + kb), y1 = *(const f4*)(a1 + kb + 4);
    bf16x8 af0 = cvt8(x0, x1), af1 = cvt8(y0, y1);
    bf16x8 b0 = *(const bf16x8*)(bp + kb);
    bf16x8 b1 = *(const bf16x8*)(bp + kb + 16 * 256);
    acc[0][0] = MFMA16(af0, b0, acc[0][0], 0, 0, 0);
    acc[0][1] = MFMA16(af0, b1, acc[0][1], 0, 0, 0);
    acc[1][0] = MFMA16(af1, b0, acc[1][0], 0, 0, 0);
    acc[1][1] = MFMA16(af1, b1, acc[1][1], 0, 0, 0);
  }
  #pragma unroll
  for (int mf = 0; mf < 2; ++mf)
    #pragma unroll
    for (int nf = 0; nf < 2; ++nf) {
      int col = c0 + wave * 32 + nf * 16 + lm;
      float bias = (col < kDPL) ? dpB[col] : 0.f;
      #pragma unroll
      for (int j = 0; j < 4; ++j) {
        int row = r0 + mf * 16 + lg * 4 + j;
        u[(size_t)row * 512 + col] = acc[mf][nf][j] + bias;
      }
    }
}

// ---------------- dp softmax over 500 cols ----------------
__global__ __launch_bounds__(128) void mmore_dpsoft(
    const float* __restrict__ u, float* __restrict__ out) {
  int bt = blockIdx.x, t = threadIdx.x;
  __shared__ float red[2];
  float v[4]; float mx = -1e30f;
  #pragma unroll
  for (int i = 0; i < 4; ++i) {
    int c = t + i * 128;
    v[i] = (c < kDPL) ? u[(size_t)bt * 512 + c] : -1e30f;
    mx = fmaxf(mx, v[i]);
  }
  #pragma unroll
  for (int off = 32; off; off >>= 1) mx = fmaxf(mx, __shfl_xor(mx, off));
  if ((t & 63) == 0) red[t >> 6] = mx;
  __syncthreads();
  mx = fmaxf(red[0], red[1]);
  __syncthreads();
  float e[4], s = 0.f;
  #pragma unroll
  for (int i = 0; i < 4; ++i) {
    int c = t + i * 128;
    e[i] = (c < kDPL) ? __expf(v[i] - mx) : 0.f;
    s += e[i];
  }
  #pragma unroll
  for (int off = 32; off; off >>= 1) s += __shfl_xor(s, off);
  if ((t & 63) == 0) red[t >> 6] = s;
  __syncthreads();
  float invS = 1.f / (red[0] + red[1]);
  #pragma unroll
  for (int i = 0; i < 4; ++i) {
    int c = t + i * 128;
    if (c < kDPL) out[(size_t)bt * kDPL + c] = e[i] * invS;
  }
}

extern "C" void kernel_launch(void* const* d_in, const int* in_sizes, int n_in,
                              void* d_out, int out_size, void* d_ws, size_t ws_size,
                              hipStream_t stream) {
  const int*   dxseqs     = (const int*)d_in[0];
  const float* dx_onehot  = (const float*)d_in[1];
  const int*   leaves     = (const int*)d_in[2];
  const int*   ancestors  = (const int*)d_in[3];
  const float* onto_table = (const float*)d_in[4];
  const float* onto_Wa    = (const float*)d_in[5];
  const float* onto_ba    = (const float*)d_in[6];
  const float* onto_Wc    = (const float*)d_in[7];
  const float* onto_bc    = (const float*)d_in[8];
  const float* ehr_table  = (const float*)d_in[9];
  const float* attn_W     = (const float*)d_in[10];
  const float* attn_b     = (const float*)d_in[11];
  const float* comb_W     = (const float*)d_in[12];
  const float* comb_b     = (const float*)d_in[13];
  const float* co_W       = (const float*)d_in[14];
  const float* co_b       = (const float*)d_in[15];
  const float* dp_W       = (const float*)d_in[16];
  const float* dp_b       = (const float*)d_in[17];
  float* out = (float*)d_out;

  // ---- workspace (float slots), ~26.4 MB total ----
  // cpart (13 * 2048 * 128 = 3,407,872 fl) aliases peR..coWT (3,956,992 fl);
  // coWT's trcvt runs AFTER creduce.
  float* ws = (float*)d_ws;
  size_t off = 0;
  auto alloc = [&](size_t n) { float* p = ws + off; off += n; return p; };
  float* onto_all = alloc((size_t)(kV + 1) * 128);              // 1,280,128
  float* s_sc     = alloc((size_t)kV * kL);                     //    60,000
  float* ehrV     = alloc((size_t)kBT * 128);                   //   262,144
  float* ontoV    = alloc((size_t)kBT * 128);                   //   262,144
  __bf16* ontoT   = (__bf16*)alloc((size_t)128 * kOntoLd / 2);  //   655,360 fl
  __bf16* attn_WT = (__bf16*)alloc((size_t)128 * 512 / 2);      //    32,768 fl
  __bf16* dpWT    = (__bf16*)alloc((size_t)512 * 256 / 2);      //    65,536 fl
  __bf16* WaT     = (__bf16*)alloc((size_t)128 * 256 / 2);      //    16,384 fl
  float* peR      = alloc((size_t)(kV + 1) * 128);              // 1,280,128
  float* poR      = alloc((size_t)(kV + 1) * 128);              // 1,280,128
  float* basep    = alloc((size_t)kBT * 128);                   //   262,144
  float* epart    = alloc((size_t)kVT * kBT * 3);               //   485,376
  float* term     = alloc(kBT);                                 //     2,048
  __bf16* coWT    = (__bf16*)alloc((size_t)kVpad * 128 / 2);    //   647,168 fl
  // time-disjoint aliases (all within peR..coWT span):
  __bf16* ot_bf = (__bf16*)peR;   // dead after scores; before cpart
  float*  cpart = peR;            // written by ontov, dead after creduce
  float*  u     = peR;            // written after pe last read (attn)
  float*  tn    = ehrV;           // written after ehrV/ontoV last reads

  // ---- prep (coWT deferred until after creduce) ----
  mmore_cvt_bf16<<<663, 256, 0, stream>>>(onto_table, ot_bf, 10600 * 128);
  mmore_trcvt<<<dim3(2, 8), 256, 0, stream>>>(onto_Wa, WaT, 256, 128, 256);
  mmore_trcvt<<<dim3(4, 8), 256, 0, stream>>>(attn_W, attn_WT, 512, 128, 512);
  mmore_trcvt<<<dim3(2, 32), 256, 0, stream>>>(dp_W, dpWT, 256, kDPL, 256);

  mmore_ehrv<<<kBT, 128, 0, stream>>>(dxseqs, ehr_table, ehrV);
  mmore_scores_mfma<<<(kV * kL) / 32, 256, 0, stream>>>(
      ot_bf, leaves, ancestors, WaT, onto_ba, onto_Wc, onto_bc, s_sc);
  mmore_onto<<<kV + 1, 128, 0, stream>>>(onto_table, ancestors, s_sc, onto_all);
  mmore_trcvt<<<dim3(80, 8), 256, 0, stream>>>(onto_all, ontoT, kV, 128, kOntoLd);
  mmore_ontov_mfma<<<128 * kC, 256, 0, stream>>>(dx_onehot, ontoT, cpart);
  mmore_creduce<<<(kBT * 128) / 256, 256, 0, stream>>>(cpart, ontoV);
  mmore_trcvt<<<dim3(1, 632), 256, 0, stream>>>(co_W, coWT, 128, kV, 128);
  mmore_loss_mfma<<<dim3(kVT, 64), 256, 0, stream>>>(ehrV, coWT, co_b, dx_onehot, epart);
  mmore_ereduce<<<kBT / 256, 256, 0, stream>>>(epart, term);
  mmore_lossfin<<<1, 256, 0, stream>>>(term, out + (size_t)kBT * kDPL);
  mmore_gemm_mfma<<<313, 256, 0, stream>>>(ehr_table, attn_WT, 512, 256, nullptr, peR, kV + 1, 0);
  mmore_gemm_mfma<<<313, 256, 0, stream>>>(onto_all, attn_WT, 512, 384, nullptr, poR, kV + 1, 0);
  mmore_gemm_mfma<<<64, 256, 0, stream>>>(ontoV, attn_WT, 512, 0, nullptr, basep, kBT, 0);
  mmore_gemm_mfma<<<64, 256, 0, stream>>>(ehrV, attn_WT, 512, 128, attn_b, basep, kBT, 1);
  mmore_attn<<<kBT, 256, 0, stream>>>(dxseqs, basep, peR, poR, comb_W, comb_b,
                                      ehr_table, onto_all, tn);
  mmore_dpgemm<<<dim3(4, 64), 256, 0, stream>>>(tn, dpWT, dp_b, u);
  mmore_dpsoft<<<kBT, 128, 0, stream>>>(u, out);
}